// Round 4
// baseline (468.500 us; speedup 1.0000x reference)
//
#include <hip/hip_runtime.h>

// CTC loss forward, B=256, T=1024, C=256, L=128, S=257, blank=255.
// Pass 1 (throughput, BW-bound): per-row softmax-denominator + max + power-of-2
//   normalization, THEN gathers the 129 needed emission values per row through
//   LDS and writes a compact pre-scaled 528B record:
//     [ (c1,c3) x 64 lanes | cB | M | pad ]   (ROWF = 132 floats)
// Pass 2 (latency-bound): one wave per batch element, linear-domain DP.
//   Cross-lane shift via DPP wave_shr:1 (pure VALU). The 16-row register
//   prefetch ring is FORCED to stay resident: __launch_bounds__(64,1) lifts
//   the VGPR budget, and sched_barrier(0) at each step end pins the ring
//   loads >=14 steps ahead of use (the compiler was sinking them to their
//   uses, collapsing the prefetch distance and exposing L2/L3 latency —
//   visible as VGPR_Count=56 < the 64+ the ring needs).

#define B_DIM 256
#define T_DIM 1024
#define C_DIM 256
#define L_DIM 128
#define ROWF  132
#define EPSF  (1e-7f)
#define CEPSF (256.0f * 1e-7f)
#define LN2F  (0.6931471805599453f)

// ---------------- pass 1: row stats + gather ----------------
__global__ __launch_bounds__(256) void row_gather_kernel(const int* __restrict__ yt,
                                                         const float* __restrict__ yp,
                                                         float* __restrict__ cw) {
    const int w    = threadIdx.x >> 6;
    const int lane = threadIdx.x & 63;
    const int row  = (blockIdx.x << 2) + w;   // 4 rows/block, all same batch b
    const int b    = row >> 10;
    __shared__ float lds[4][C_DIM];

    const float4 v = ((const float4*)(yp + (size_t)row * C_DIM))[lane];
    float e0 = v.x + EPSF, e1 = v.y + EPSF, e2 = v.z + EPSF, e3 = v.w + EPSF;
    float s  = v.x + v.y + v.z + v.w;
    float mx = fmaxf(fmaxf(e0, e1), fmaxf(e2, e3));
    #pragma unroll
    for (int d = 1; d < 64; d <<= 1) {
        s  += __shfl_xor(s, d, 64);
        mx  = fmaxf(mx, __shfl_xor(mx, d, 64));
    }
    const float invsum = 1.0f / (s + CEPSF);
    const float tm = mx * invsum;                      // max normalized prob, (0,1]
    const int   M  = (__float_as_int(tm) >> 23) - 127; // ilogb(tm) <= 0
    const float srow = invsum * __int_as_float((127 - M) << 23);  // exact 2^-M scale
    e0 *= srow; e1 *= srow; e2 *= srow; e3 *= srow;

    *(float4*)&lds[w][lane << 2] = make_float4(e0, e1, e2, e3);
    const int2 lp = ((const int2*)(yt + ((size_t)b << 7)))[lane];  // lab[2l], lab[2l+1]
    __syncthreads();

    float* rb = cw + (size_t)row * ROWF;
    ((float2*)rb)[lane] = make_float2(lds[w][lp.x], lds[w][lp.y]);
    if (lane == 63)                      // class 255 (blank) = this lane's v.w
        ((float2*)rb)[64] = make_float2(e3, (float)M);
}

// ---------------- pass 2: DP ----------------
__global__ __launch_bounds__(64, 1) void ctc_dp_kernel(const int* __restrict__ yt,
                                                       const float* __restrict__ cw,
                                                       float* __restrict__ out)
{
    const int b = blockIdx.x, lane = threadIdx.x;
    const float* base = cw + (size_t)b * (T_DIM * ROWF);
    const int* lab = yt + b * L_DIM;
    const int lab1 = lab[2 * lane];
    const int lab3 = lab[2 * lane + 1];
    const int labm = (lane == 0) ? -1 : lab[2 * lane - 1];
    const float sk1 = (lab1 != labm) ? 1.0f : 0.0f;
    const float sk3 = (lab3 != lab1) ? 1.0f : 0.0f;
    const float2* pcl = (const float2*)base + lane;  // (c1,c3), row stride 66 float2
    const float2* pbm = (const float2*)base + 64;    // (cB, M), row stride 66 float2
    const bool l0 = (lane == 0);

    // 16-row register prefetch ring: 2 loads/row (coalesced pair + broadcast)
    float2 rc[16], rm[16];
#pragma unroll
    for (int u = 0; u < 16; ++u) { rc[u] = pcl[u * 66]; rm[u] = pbm[u * 66]; }
    __builtin_amdgcn_sched_barrier(0);   // keep prologue loads issued up front

    float Mtot = 0.0f, Rtot = 0.0f;
    float c1, c3, cB, n1l, n3l, nB;
    float a0, a1, a2 = 0.0f, a3 = 0.0f, a4 = 0.0f;

#define LPL(S, o1, o3, oB) do {                 \
        Mtot += rm[S].y;                        \
        (o1) = rc[S].x;                         \
        (o3) = rc[S].y;                         \
        (oB) = rm[S].x; } while (0)

    { float i1, i3, iB; LPL(0, i1, i3, iB);
      a0 = l0 ? iB : 0.0f; a1 = l0 ? i1 : 0.0f; }
    LPL(1, c1, c3, cB);
    LPL(2, n1l, n3l, nB);

    float m = 1.0f, w = 1.0f, s1f = 1.0f, s2f = 1.0f;

    // DP step t: alphas advance with row t; prefetch row t+15; stage row t+2.
    // prev (= lane-1's pre-update a3) via DPP wave_shr:1; bound_ctrl=true
    // zeroes lane 0. Reading a3 AFTER the APPLY rescale reproduces the exact
    // multiply sequence the old bpermute path applied to prev.
    // sched_barrier(0) at the end pins this step's prefetch loads from being
    // sunk toward their consumption 15 steps later.
#define STEP(T_, SPF_, S2_, DOPF_, DOLP_, APPLY_) do {                     \
        if (APPLY_) {                                                      \
            a0 *= s1f; a1 *= s1f; a2 *= s1f; a3 *= s1f; a4 *= s1f;         \
            a0 *= s2f; a1 *= s2f; a2 *= s2f; a3 *= s2f; a4 *= s2f; }       \
        float prev = __int_as_float(__builtin_amdgcn_update_dpp(           \
                        0, __float_as_int(a3), 0x138, 0xf, 0xf, true));    \
        float x3 = (a3 + a2 + sk3 * a1) * c3;                              \
        float x0 = (a0 + prev) * cB;                                       \
        float x1 = (a1 + a0 + sk1 * prev) * c1;                            \
        float x2 = (a2 + a1) * cB;                                         \
        float x4 = (a4 + a3) * cB;                                         \
        a0 = x0; a1 = x1; a2 = x2; a3 = x3; a4 = x4;                       \
        if (DOPF_) { const int o_ = ((T_) + 15) * 66;                      \
            rc[SPF_] = pcl[o_]; rm[SPF_] = pbm[o_]; }                      \
        c1 = n1l; c3 = n3l; cB = nB;                                       \
        if (DOLP_) { LPL(S2_, n1l, n3l, nB); }                             \
        __builtin_amdgcn_sched_barrier(0);                                 \
    } while (0)

    // rescale-pipeline stages, one per 2 steps (2-step gap hides ds latency)
#define STAGES(K_)                                                          \
        if ((K_) == 0)  { m = fmaxf(fmaxf(a0, a1), fmaxf(fmaxf(a2, a3), a4)); \
                          w = __shfl_xor(m, 1, 64); }                       \
        if ((K_) == 2)  { m = fmaxf(m, w); w = __shfl_xor(m, 2, 64); }      \
        if ((K_) == 4)  { m = fmaxf(m, w); w = __shfl_xor(m, 4, 64); }      \
        if ((K_) == 6)  { m = fmaxf(m, w); w = __shfl_xor(m, 8, 64); }      \
        if ((K_) == 8)  { m = fmaxf(m, w); w = __shfl_xor(m, 16, 64); }     \
        if ((K_) == 10) { m = fmaxf(m, w); w = __shfl_xor(m, 32, 64); }     \
        if ((K_) == 12) { m = fmaxf(m, w);                                  \
                          int E  = (__float_as_int(m) >> 23) - 127;         \
                          int sh = 60 - E;                                  \
                          Rtot -= (float)sh;                                \
                          int sh1 = sh >> 1, sh2 = sh - sh1;                \
                          s1f = __int_as_float((sh1 + 127) << 23);          \
                          s2f = __int_as_float((sh2 + 127) << 23); }

    // peeled first chunk: t = 1..15 (no rescale yet)
#pragma unroll
    for (int k = 1; k <= 15; ++k) {
        STEP(k, (k - 1) & 15, (k + 2) & 15, 1, 1, 0);
    }

    // main chunks: t = 16 .. 1007
    for (int t0 = 16; t0 <= 992; t0 += 16) {
#pragma unroll
        for (int k = 0; k < 16; ++k) {
            STAGES(k)
            STEP(t0 + k, (k + 15) & 15, (k + 2) & 15, 1, 1, (k == 13));
        }
    }

    // last chunk: t = 1008..1023
    {
        const int t0 = 1008;
#pragma unroll
        for (int k = 0; k < 16; ++k) {
            STAGES(k)
            STEP(t0 + k, (k + 15) & 15, (k + 2) & 15, (k == 0), (k <= 13), (k == 13));
        }
    }

    if (lane == 63) {
        float v = a3 + a4;   // states 255 and 256
        out[b] = -(log2f(v) + Mtot + Rtot) * LN2F;
    }
#undef STEP
#undef STAGES
#undef LPL
}

extern "C" void kernel_launch(void* const* d_in, const int* in_sizes, int n_in,
                              void* d_out, int out_size, void* d_ws, size_t ws_size,
                              hipStream_t stream) {
    const int*   yt = (const int*)d_in[0];     // y_true [256,128] int32
    const float* yp = (const float*)d_in[1];   // y_pred [256,1024,256] f32
    float* out = (float*)d_out;                // [256,1] f32
    float* cw = (float*)d_ws;                  // compact rows: 256*1024*132*4 = 132 MiB
    (void)in_sizes; (void)n_in; (void)out_size; (void)ws_size;
    row_gather_kernel<<<dim3((B_DIM * T_DIM) / 4), dim3(256), 0, stream>>>(yt, yp, cw);
    ctc_dp_kernel<<<dim3(B_DIM), dim3(64), 0, stream>>>(yt, cw, out);
}

// Round 5
// 436.072 us; speedup vs baseline: 1.0744x; 1.0744x over previous
//
#include <hip/hip_runtime.h>

// CTC loss forward, B=256, T=1024, C=256, L=128, S=257, blank=255.
// Pass 1 (throughput, BW-bound): per-row softmax-denominator + max + power-of-2
//   normalization, THEN gathers the 129 needed emission values per row through
//   LDS and writes a compact pre-scaled 528B record:
//     [ (c1,c3) x 64 lanes | (cB,M) | (cB,M) ]   (ROWF = 132 floats; the
//   (cB,M) pair is DUPLICATED in slots 64 and 65 so the DP can read it with a
//   genuinely divergent per-lane address).
// Pass 2 (latency-bound): one wave per batch element, linear-domain DP.
//   KEY FIX this round: the (cB,M) ring load previously had a wave-uniform
//   address -> hipcc emitted s_load (SMEM). SMEM returns OUT OF ORDER, so
//   every use forced s_waitcnt lgkmcnt(0), draining all 16 ring prefetches
//   -> one full scalar-cache-miss latency (~280 cyc) exposed per step.
//   Now lanes<32 read slot 64 and lanes>=32 read slot 65 (mbcnt-derived
//   divergent offset, same cache line) -> vector path, in-order counted
//   vmcnt, prefetch ring actually hides latency. Cross-lane max-reduce is
//   also moved off the DS pipe: quad_perm/row_ror DPP for xor1/2/4-span/8,
//   only xor16/xor32 remain as gapped __shfl_xor.

#define B_DIM 256
#define T_DIM 1024
#define C_DIM 256
#define L_DIM 128
#define ROWF  132
#define EPSF  (1e-7f)
#define CEPSF (256.0f * 1e-7f)
#define LN2F  (0.6931471805599453f)

// ---------------- pass 1: row stats + gather ----------------
__global__ __launch_bounds__(256) void row_gather_kernel(const int* __restrict__ yt,
                                                         const float* __restrict__ yp,
                                                         float* __restrict__ cw) {
    const int w    = threadIdx.x >> 6;
    const int lane = threadIdx.x & 63;
    const int row  = (blockIdx.x << 2) + w;   // 4 rows/block, all same batch b
    const int b    = row >> 10;
    __shared__ float lds[4][C_DIM];

    const float4 v = ((const float4*)(yp + (size_t)row * C_DIM))[lane];
    float e0 = v.x + EPSF, e1 = v.y + EPSF, e2 = v.z + EPSF, e3 = v.w + EPSF;
    float s  = v.x + v.y + v.z + v.w;
    float mx = fmaxf(fmaxf(e0, e1), fmaxf(e2, e3));
    #pragma unroll
    for (int d = 1; d < 64; d <<= 1) {
        s  += __shfl_xor(s, d, 64);
        mx  = fmaxf(mx, __shfl_xor(mx, d, 64));
    }
    const float invsum = 1.0f / (s + CEPSF);
    const float tm = mx * invsum;                      // max normalized prob, (0,1]
    const int   M  = (__float_as_int(tm) >> 23) - 127; // ilogb(tm) <= 0
    const float srow = invsum * __int_as_float((127 - M) << 23);  // exact 2^-M scale
    e0 *= srow; e1 *= srow; e2 *= srow; e3 *= srow;

    *(float4*)&lds[w][lane << 2] = make_float4(e0, e1, e2, e3);
    const int2 lp = ((const int2*)(yt + ((size_t)b << 7)))[lane];  // lab[2l], lab[2l+1]
    __syncthreads();

    float* rb = cw + (size_t)row * ROWF;
    ((float2*)rb)[lane] = make_float2(lds[w][lp.x], lds[w][lp.y]);
    if (lane == 63)                      // class 255 (blank) = this lane's v.w
        ((float4*)rb)[32] = make_float4(e3, (float)M, e3, (float)M); // slots 64+65
}

// ---------------- pass 2: DP ----------------
__global__ __launch_bounds__(64, 1) void ctc_dp_kernel(const int* __restrict__ yt,
                                                       const float* __restrict__ cw,
                                                       float* __restrict__ out)
{
    const int b = blockIdx.x, lane = threadIdx.x;
    const float* base = cw + (size_t)b * (T_DIM * ROWF);
    const int* lab = yt + b * L_DIM;
    const int lab1 = lab[2 * lane];
    const int lab3 = lab[2 * lane + 1];
    const int labm = (lane == 0) ? -1 : lab[2 * lane - 1];
    const float sk1 = (lab1 != labm) ? 1.0f : 0.0f;
    const float sk3 = (lab3 != lab1) ? 1.0f : 0.0f;
    const float2* pcl = (const float2*)base + lane;  // (c1,c3), row stride 66 float2
    // Genuinely divergent zero/one: mbcnt_lo(bit31, 0) = 0 for lanes<32, 1 for
    // lanes>=32. Lane-dependent intrinsic -> uniformizer cannot turn the rm
    // stream into an s_load. Slots 64 and 65 hold identical (cB, M).
    const int dz = (int)__builtin_amdgcn_mbcnt_lo(1u << 31, 0u);
    const float2* pbm = (const float2*)base + 64 + dz;
    const bool l0 = (lane == 0);

    // 16-row register prefetch ring: 2 VMEM loads/row (pair + near-broadcast)
    float2 rc[16], rm[16];
#pragma unroll
    for (int u = 0; u < 16; ++u) { rc[u] = pcl[u * 66]; rm[u] = pbm[u * 66]; }
    __builtin_amdgcn_sched_barrier(0);   // keep prologue loads issued up front

    float Mtot = 0.0f, Rtot = 0.0f;
    float c1, c3, cB, n1l, n3l, nB;
    float a0, a1, a2 = 0.0f, a3 = 0.0f, a4 = 0.0f;

#define LPL(S, o1, o3, oB) do {                 \
        Mtot += rm[S].y;                        \
        (o1) = rc[S].x;                         \
        (o3) = rc[S].y;                         \
        (oB) = rm[S].x; } while (0)

    { float i1, i3, iB; LPL(0, i1, i3, iB);
      a0 = l0 ? iB : 0.0f; a1 = l0 ? i1 : 0.0f; }
    LPL(1, c1, c3, cB);
    LPL(2, n1l, n3l, nB);

    float m = 1.0f, w = 1.0f, s1f = 1.0f, s2f = 1.0f;

    // DPP-based partial max: m = max(m, dpp_move(m)) — pure VALU, no DS pipe.
#define DPPMAX(CTRL_) do {                                                 \
        int t_ = __builtin_amdgcn_update_dpp(                              \
                     0, __float_as_int(m), (CTRL_), 0xf, 0xf, true);       \
        m = fmaxf(m, __int_as_float(t_)); } while (0)

    // DP step t: alphas advance with row t; prefetch row t+15; stage row t+2.
    // prev (= lane-1's pre-update a3) via DPP wave_shr:1; bound_ctrl=true
    // zeroes lane 0. Reading a3 AFTER the APPLY rescale reproduces the exact
    // multiply sequence of the original bpermute path.
#define STEP(T_, SPF_, S2_, DOPF_, DOLP_, APPLY_) do {                     \
        if (APPLY_) {                                                      \
            a0 *= s1f; a1 *= s1f; a2 *= s1f; a3 *= s1f; a4 *= s1f;         \
            a0 *= s2f; a1 *= s2f; a2 *= s2f; a3 *= s2f; a4 *= s2f; }       \
        float prev = __int_as_float(__builtin_amdgcn_update_dpp(           \
                        0, __float_as_int(a3), 0x138, 0xf, 0xf, true));    \
        float x3 = (a3 + a2 + sk3 * a1) * c3;                              \
        float x0 = (a0 + prev) * cB;                                       \
        float x1 = (a1 + a0 + sk1 * prev) * c1;                            \
        float x2 = (a2 + a1) * cB;                                         \
        float x4 = (a4 + a3) * cB;                                         \
        a0 = x0; a1 = x1; a2 = x2; a3 = x3; a4 = x4;                       \
        if (DOPF_) { const int o_ = ((T_) + 15) * 66;                      \
            rc[SPF_] = pcl[o_]; rm[SPF_] = pbm[o_]; }                      \
        c1 = n1l; c3 = n3l; cB = nB;                                       \
        if (DOLP_) { LPL(S2_, n1l, n3l, nB); }                             \
        __builtin_amdgcn_sched_barrier(0);                                 \
    } while (0)

    // rescale pipeline: lane-local max -> xor1,xor2 (quad_perm), quad->row
    // (row_ror:4, row_ror:8 — valid: values are quad-uniform there), then
    // xor16/xor32 via __shfl_xor with 2-step consumption gaps (DS latency
    // hidden), factor finalized at k==12, applied at k==13.
#define STAGES(K_)                                                          \
        if ((K_) == 0)  { m = fmaxf(fmaxf(a0, a1), fmaxf(fmaxf(a2, a3), a4)); \
                          DPPMAX(0xB1); }              /* quad_perm 1,0,3,2 */ \
        if ((K_) == 2)  { DPPMAX(0x4E); }              /* quad_perm 2,3,0,1 */ \
        if ((K_) == 4)  { DPPMAX(0x124); }             /* row_ror:4  */        \
        if ((K_) == 6)  { DPPMAX(0x128);               /* row_ror:8  */        \
                          w = __shfl_xor(m, 16, 64); }                      \
        if ((K_) == 8)  { m = fmaxf(m, w); w = __shfl_xor(m, 32, 64); }     \
        if ((K_) == 10) { m = fmaxf(m, w); }                                \
        if ((K_) == 12) { int E  = (__float_as_int(m) >> 23) - 127;         \
                          int sh = 60 - E;                                  \
                          Rtot -= (float)sh;                                \
                          int sh1 = sh >> 1, sh2 = sh - sh1;                \
                          s1f = __int_as_float((sh1 + 127) << 23);          \
                          s2f = __int_as_float((sh2 + 127) << 23); }

    // peeled first chunk: t = 1..15 (no rescale yet)
#pragma unroll
    for (int k = 1; k <= 15; ++k) {
        STEP(k, (k - 1) & 15, (k + 2) & 15, 1, 1, 0);
    }

    // main chunks: t = 16 .. 1007
    for (int t0 = 16; t0 <= 992; t0 += 16) {
#pragma unroll
        for (int k = 0; k < 16; ++k) {
            STAGES(k)
            STEP(t0 + k, (k + 15) & 15, (k + 2) & 15, 1, 1, (k == 13));
        }
    }

    // last chunk: t = 1008..1023
    {
        const int t0 = 1008;
#pragma unroll
        for (int k = 0; k < 16; ++k) {
            STAGES(k)
            STEP(t0 + k, (k + 15) & 15, (k + 2) & 15, (k == 0), (k <= 13), (k == 13));
        }
    }

    if (lane == 63) {
        float v = a3 + a4;   // states 255 and 256
        out[b] = -(log2f(v) + Mtot + Rtot) * LN2F;
    }
#undef STEP
#undef STAGES
#undef DPPMAX
#undef LPL
}

extern "C" void kernel_launch(void* const* d_in, const int* in_sizes, int n_in,
                              void* d_out, int out_size, void* d_ws, size_t ws_size,
                              hipStream_t stream) {
    const int*   yt = (const int*)d_in[0];     // y_true [256,128] int32
    const float* yp = (const float*)d_in[1];   // y_pred [256,1024,256] f32
    float* out = (float*)d_out;                // [256,1] f32
    float* cw = (float*)d_ws;                  // compact rows: 256*1024*132*4 = 132 MiB
    (void)in_sizes; (void)n_in; (void)out_size; (void)ws_size;
    row_gather_kernel<<<dim3((B_DIM * T_DIM) / 4), dim3(256), 0, stream>>>(yt, yp, cw);
    ctc_dp_kernel<<<dim3(B_DIM), dim3(64), 0, stream>>>(yt, cw, out);
}